// Round 1
// baseline (395.499 us; speedup 1.0000x reference)
//
#include <hip/hip_runtime.h>
#include <math.h>

#define BATCH 8
#define CCH   256
#define TT    32
#define HWSZ  784      // 28*28
#define HID   512
#define EMB   32
#define KBINS 4
#define SCALEF 5.0f
#define EPSN  1e-12f

// ---------------------------------------------------------------------------
// Kernel A: pooled[b,c,t] = mean over 784 contiguous elements of x[b,c,t,:,:]
// One wave (64 lanes) per (b,c,t) row; float4 loads (196 per row).
// ---------------------------------------------------------------------------
__global__ void pool_kernel(const float* __restrict__ x, float* __restrict__ pooled) {
    const int wave = threadIdx.x >> 6;
    const int lane = threadIdx.x & 63;
    const int row  = blockIdx.x * 4 + wave;            // [0, B*C*T)
    const float4* xp = (const float4*)(x + (size_t)row * HWSZ);
    float s = 0.f;
    for (int f = lane; f < 196; f += 64) {
        float4 v = xp[f];
        s += v.x + v.y + v.z + v.w;
    }
#pragma unroll
    for (int off = 32; off > 0; off >>= 1) s += __shfl_down(s, off);
    if (lane == 0) pooled[row] = s * (1.0f / 784.0f);
}

// ---------------------------------------------------------------------------
// Kernel B: h[b,hid,t] = hswish(sum_c W1[hid,c]*pooled[b,c,t] + b1[hid])
// Thread per (hid,t) output; block covers 8 hid rows x 32 t.
// ---------------------------------------------------------------------------
__global__ void fc1_kernel(const float* __restrict__ W1, const float* __restrict__ b1,
                           const float* __restrict__ pooled, float* __restrict__ h) {
    const int b   = blockIdx.x >> 6;
    const int seg = blockIdx.x & 63;
    const int t   = threadIdx.x & 31;
    const int hid = seg * 8 + (threadIdx.x >> 5);
    const float* pb = pooled + (size_t)b * CCH * TT + t;
    const float* w  = W1 + (size_t)hid * CCH;
    float acc = 0.f;
#pragma unroll 4
    for (int c = 0; c < CCH; c++) acc += w[c] * pb[c * TT];
    acc += b1[hid];
    float r = fminf(fmaxf(acc + 3.0f, 0.0f), 6.0f);
    h[((size_t)b * HID + hid) * TT + t] = acc * r * (1.0f / 6.0f);
}

// ---------------------------------------------------------------------------
// Kernel C: one block per batch. fc2 -> l2norm(embd) -> neighbor sims ->
// 3rd-smallest threshold (top_k semantics incl. duplicates) -> grouping ->
// centers -> l2norm -> similarities -> softmax -> per-group weight norm.
// Writes nw[b][t][k].
// ---------------------------------------------------------------------------
__global__ void group_kernel(const float* __restrict__ W2, const float* __restrict__ b2,
                             const float* __restrict__ h, float* __restrict__ nw) {
    __shared__ float se[EMB][TT + 1];    // embds, then normalized embds
    __shared__ float ns[TT];             // neighbor sims (31 used)
    __shared__ float tmpns[TT];          // scratch for top-k
    __shared__ float colinv[TT];
    __shared__ float cs[EMB][KBINS];     // centers
    __shared__ float wts[TT][KBINS];
    __shared__ float gsize[KBINS];
    __shared__ float kfac[KBINS];
    __shared__ int   gid[TT];

    const int b   = blockIdx.x;
    const int tid = threadIdx.x;
    const float* hb = h + (size_t)b * HID * TT;

    // fc2: embds[e,t] = sum_hid W2[e,hid]*h[b,hid,t] + b2[e]   (1024 outputs)
    for (int i = 0; i < 4; i++) {
        int o = tid + 256 * i;
        int e = o >> 5, t = o & 31;
        const float* w  = W2 + (size_t)e * HID;
        const float* hp = hb + t;
        float acc = 0.f;
        for (int hd = 0; hd < HID; hd++) acc += w[hd] * hp[hd * TT];
        se[e][t] = acc + b2[e];
    }
    __syncthreads();

    // column l2 norms over e
    if (tid < TT) {
        float s = 0.f;
        for (int e = 0; e < EMB; e++) { float v = se[e][tid]; s += v * v; }
        colinv[tid] = 1.0f / fmaxf(sqrtf(s), EPSN);
    }
    __syncthreads();
    for (int i = tid; i < EMB * TT; i += 256) {
        int e = i >> 5, t = i & 31;
        se[e][t] *= colinv[t];
    }
    __syncthreads();

    // neighbor similarities ns[t] = <ne[:,t], ne[:,t+1]>
    if (tid < TT - 1) {
        float s = 0.f;
        for (int e = 0; e < EMB; e++) s += se[e][tid] * se[e][tid + 1];
        ns[tid] = s;
    }
    __syncthreads();

    // threshold = 3rd smallest of ns (counting duplicates, = top_k semantics)
    if (tid == 0) {
        for (int i = 0; i < TT - 1; i++) tmpns[i] = ns[i];
        float thr = 0.f;
        for (int p = 0; p < KBINS - 1; p++) {
            int jm = 0; float m = tmpns[0];
            for (int i = 1; i < TT - 1; i++) if (tmpns[i] < m) { m = tmpns[i]; jm = i; }
            thr = m;
            tmpns[jm] = __builtin_inff();
        }
        // groups = cumsum of breaks; break at t iff !(ns[t-1] > thr)
        int g = 0; gid[0] = 0;
        for (int t = 1; t < TT; t++) { if (!(ns[t - 1] > thr)) g++; gid[t] = g; }
        for (int k = 0; k < KBINS; k++) {
            float c = 0.f;
            for (int t = 0; t < TT; t++) if (gid[t] == k) c += 1.0f;
            gsize[k] = c;
        }
    }
    __syncthreads();

    // centers_sum / size
    if (tid < EMB * KBINS) {
        int e = tid >> 2, k = tid & 3;
        float s = 0.f;
        for (int t = 0; t < TT; t++) if (gid[t] == k) s += se[e][t];
        cs[e][k] = s / gsize[k];
    }
    __syncthreads();
    if (tid < KBINS) {
        float s = 0.f;
        for (int e = 0; e < EMB; e++) { float v = cs[e][tid]; s += v * v; }
        kfac[tid] = 1.0f / fmaxf(sqrtf(s), EPSN);
    }
    __syncthreads();
    if (tid < EMB * KBINS) {
        int e = tid >> 2, k = tid & 3;
        cs[e][k] *= kfac[k];
    }
    __syncthreads();

    // similarities (scaled by SCALEF)
    if (tid < TT * KBINS) {
        int t = tid >> 2, k = tid & 3;
        float s = 0.f;
        for (int e = 0; e < EMB; e++) s += se[e][t] * cs[e][k];
        wts[t][k] = s * SCALEF;
    }
    __syncthreads();
    // softmax over k per t
    if (tid < TT) {
        float m = wts[tid][0];
        for (int k = 1; k < KBINS; k++) m = fmaxf(m, wts[tid][k]);
        float ex[KBINS]; float sum = 0.f;
        for (int k = 0; k < KBINS; k++) { ex[k] = expf(wts[tid][k] - m); sum += ex[k]; }
        float inv = 1.0f / sum;
        for (int k = 0; k < KBINS; k++) wts[tid][k] = ex[k] * inv;
    }
    __syncthreads();
    // per-group scale = 1 / sum_t weights
    if (tid < KBINS) {
        float s = 0.f;
        for (int t = 0; t < TT; t++) s += wts[t][tid];
        kfac[tid] = (s > 0.f) ? (1.0f / s) : 1.0f;
    }
    __syncthreads();
    if (tid < TT * KBINS) {
        int t = tid >> 2, k = tid & 3;
        nw[((size_t)b * TT + t) * KBINS + k] = wts[t][k] * kfac[k];
    }
}

// ---------------------------------------------------------------------------
// Kernel D: out[b,c,k,hw] = sum_t x[b,c,t,hw] * nw[b,t,k]
// One block per (b,c); thread per float4 position (196 active of 256).
// ---------------------------------------------------------------------------
__global__ void out_kernel(const float* __restrict__ x, const float* __restrict__ nw,
                           float* __restrict__ out) {
    __shared__ float w[TT * KBINS];
    const int b = blockIdx.x >> 8;
    const int c = blockIdx.x & 255;
    if (threadIdx.x < TT * KBINS) w[threadIdx.x] = nw[(size_t)b * TT * KBINS + threadIdx.x];
    __syncthreads();
    const int f = threadIdx.x;
    if (f >= 196) return;
    const float4* xp = (const float4*)(x + ((size_t)(b * CCH + c) * TT) * HWSZ);
    float4 acc[KBINS];
#pragma unroll
    for (int k = 0; k < KBINS; k++) { acc[k].x = 0.f; acc[k].y = 0.f; acc[k].z = 0.f; acc[k].w = 0.f; }
    for (int t = 0; t < TT; t++) {
        float4 v = xp[t * 196 + f];
#pragma unroll
        for (int k = 0; k < KBINS; k++) {
            float wk = w[t * KBINS + k];
            acc[k].x += v.x * wk;
            acc[k].y += v.y * wk;
            acc[k].z += v.z * wk;
            acc[k].w += v.w * wk;
        }
    }
    float4* op = (float4*)(out + ((size_t)(b * CCH + c) * KBINS) * HWSZ);
#pragma unroll
    for (int k = 0; k < KBINS; k++) op[k * 196 + f] = acc[k];
}

extern "C" void kernel_launch(void* const* d_in, const int* in_sizes, int n_in,
                              void* d_out, int out_size, void* d_ws, size_t ws_size,
                              hipStream_t stream) {
    const float* x  = (const float*)d_in[0];
    const float* W1 = (const float*)d_in[1];
    const float* b1 = (const float*)d_in[2];
    const float* W2 = (const float*)d_in[3];
    const float* b2 = (const float*)d_in[4];
    float* out = (float*)d_out;

    float* ws     = (float*)d_ws;
    float* pooled = ws;                                // B*C*T   = 65536
    float* h      = pooled + BATCH * CCH * TT;         // B*HID*T = 131072
    float* nw     = h + BATCH * HID * TT;              // B*T*K   = 1024

    pool_kernel<<<BATCH * CCH * TT / 4, 256, 0, stream>>>(x, pooled);
    fc1_kernel<<<BATCH * 64, 256, 0, stream>>>(W1, b1, pooled, h);
    group_kernel<<<BATCH, 256, 0, stream>>>(W2, b2, h, nw);
    out_kernel<<<BATCH * CCH, 256, 0, stream>>>(x, nw, out);
}

// Round 2
// 360.836 us; speedup vs baseline: 1.0961x; 1.0961x over previous
//
#include <hip/hip_runtime.h>
#include <math.h>

#define BATCH 8
#define CCH   256
#define TT    32
#define HWSZ  784      // 28*28
#define HID   512
#define EMB   32
#define KBINS 4
#define SCALEF 5.0f
#define EPSN  1e-12f

// ---------------------------------------------------------------------------
// Kernel A: pooled[b,c,t] = mean over 784 contiguous elements of x[b,c,t,:,:]
// One wave (64 lanes) per (b,c,t) row; float4 loads (196 per row).
// ---------------------------------------------------------------------------
__global__ void pool_kernel(const float* __restrict__ x, float* __restrict__ pooled) {
    const int wave = threadIdx.x >> 6;
    const int lane = threadIdx.x & 63;
    const int row  = blockIdx.x * 4 + wave;            // [0, B*C*T)
    const float4* xp = (const float4*)(x + (size_t)row * HWSZ);
    float s = 0.f;
    for (int f = lane; f < 196; f += 64) {
        float4 v = xp[f];
        s += v.x + v.y + v.z + v.w;
    }
#pragma unroll
    for (int off = 32; off > 0; off >>= 1) s += __shfl_down(s, off);
    if (lane == 0) pooled[row] = s * (1.0f / 784.0f);
}

// ---------------------------------------------------------------------------
// Kernel B: h[b,hid,t] = hswish(sum_c W1[hid,c]*pooled[b,c,t] + b1[hid])
// Thread per (hid,t) output; block covers 8 hid rows x 32 t.
// ---------------------------------------------------------------------------
__global__ void fc1_kernel(const float* __restrict__ W1, const float* __restrict__ b1,
                           const float* __restrict__ pooled, float* __restrict__ h) {
    const int b   = blockIdx.x >> 6;
    const int seg = blockIdx.x & 63;
    const int t   = threadIdx.x & 31;
    const int hid = seg * 8 + (threadIdx.x >> 5);
    const float* pb = pooled + (size_t)b * CCH * TT + t;
    const float* w  = W1 + (size_t)hid * CCH;
    float acc = 0.f;
#pragma unroll 8
    for (int c = 0; c < CCH; c++) acc += w[c] * pb[c * TT];
    acc += b1[hid];
    float r = fminf(fmaxf(acc + 3.0f, 0.0f), 6.0f);
    h[((size_t)b * HID + hid) * TT + t] = acc * r * (1.0f / 6.0f);
}

// ---------------------------------------------------------------------------
// Kernel B2: embds[b,e,t] = sum_hid W2[e,hid]*h[b,hid,t] + b2[e]
// 8192 outputs, thread per output, 32 blocks (parallel across CUs).
// ---------------------------------------------------------------------------
__global__ void fc2_kernel(const float* __restrict__ W2, const float* __restrict__ b2,
                           const float* __restrict__ h, float* __restrict__ embds) {
    const int o = blockIdx.x * 256 + threadIdx.x;      // [0, 8192)
    const int b = o >> 10;
    const int e = (o >> 5) & 31;
    const int t = o & 31;
    const float* w  = W2 + (size_t)e * HID;
    const float* hp = h + (size_t)b * HID * TT + t;
    float acc = 0.f;
#pragma unroll 8
    for (int hd = 0; hd < HID; hd++) acc += w[hd] * hp[hd * TT];
    embds[o] = acc + b2[e];
}

// ---------------------------------------------------------------------------
// Kernel C: one block per batch, starting from embds.
// l2norm -> neighbor sims -> 3rd-smallest threshold (top_k incl. duplicates)
// -> grouping -> centers -> l2norm -> similarities -> softmax -> weight norm.
// ---------------------------------------------------------------------------
__global__ void group_kernel(const float* __restrict__ embds, float* __restrict__ nw) {
    __shared__ float se[EMB][TT + 1];
    __shared__ float ns[TT];
    __shared__ float tmpns[TT];
    __shared__ float colinv[TT];
    __shared__ float cs[EMB][KBINS];
    __shared__ float wts[TT][KBINS];
    __shared__ float gsize[KBINS];
    __shared__ float kfac[KBINS];
    __shared__ int   gid[TT];

    const int b   = blockIdx.x;
    const int tid = threadIdx.x;

    // load embds into LDS
    for (int i = tid; i < EMB * TT; i += 256) {
        se[i >> 5][i & 31] = embds[(size_t)b * EMB * TT + i];
    }
    __syncthreads();

    // column l2 norms over e
    if (tid < TT) {
        float s = 0.f;
        for (int e = 0; e < EMB; e++) { float v = se[e][tid]; s += v * v; }
        colinv[tid] = 1.0f / fmaxf(sqrtf(s), EPSN);
    }
    __syncthreads();
    for (int i = tid; i < EMB * TT; i += 256) {
        int e = i >> 5, t = i & 31;
        se[e][t] *= colinv[t];
    }
    __syncthreads();

    // neighbor similarities ns[t] = <ne[:,t], ne[:,t+1]>
    if (tid < TT - 1) {
        float s = 0.f;
        for (int e = 0; e < EMB; e++) s += se[e][tid] * se[e][tid + 1];
        ns[tid] = s;
    }
    __syncthreads();

    // threshold = 3rd smallest of ns (duplicate-counting = top_k semantics)
    if (tid == 0) {
        for (int i = 0; i < TT - 1; i++) tmpns[i] = ns[i];
        float thr = 0.f;
        for (int p = 0; p < KBINS - 1; p++) {
            int jm = 0; float m = tmpns[0];
            for (int i = 1; i < TT - 1; i++) if (tmpns[i] < m) { m = tmpns[i]; jm = i; }
            thr = m;
            tmpns[jm] = __builtin_inff();
        }
        int g = 0; gid[0] = 0;
        for (int t = 1; t < TT; t++) { if (!(ns[t - 1] > thr)) g++; gid[t] = g; }
        for (int k = 0; k < KBINS; k++) {
            float c = 0.f;
            for (int t = 0; t < TT; t++) if (gid[t] == k) c += 1.0f;
            gsize[k] = c;
        }
    }
    __syncthreads();

    // centers_sum / size
    if (tid < EMB * KBINS) {
        int e = tid >> 2, k = tid & 3;
        float s = 0.f;
        for (int t = 0; t < TT; t++) if (gid[t] == k) s += se[e][t];
        cs[e][k] = s / gsize[k];
    }
    __syncthreads();
    if (tid < KBINS) {
        float s = 0.f;
        for (int e = 0; e < EMB; e++) { float v = cs[e][tid]; s += v * v; }
        kfac[tid] = 1.0f / fmaxf(sqrtf(s), EPSN);
    }
    __syncthreads();
    if (tid < EMB * KBINS) {
        int e = tid >> 2, k = tid & 3;
        cs[e][k] *= kfac[k];
    }
    __syncthreads();

    // similarities (scaled)
    if (tid < TT * KBINS) {
        int t = tid >> 2, k = tid & 3;
        float s = 0.f;
        for (int e = 0; e < EMB; e++) s += se[e][t] * cs[e][k];
        wts[t][k] = s * SCALEF;
    }
    __syncthreads();
    // softmax over k per t
    if (tid < TT) {
        float m = wts[tid][0];
        for (int k = 1; k < KBINS; k++) m = fmaxf(m, wts[tid][k]);
        float ex[KBINS]; float sum = 0.f;
        for (int k = 0; k < KBINS; k++) { ex[k] = expf(wts[tid][k] - m); sum += ex[k]; }
        float inv = 1.0f / sum;
        for (int k = 0; k < KBINS; k++) wts[tid][k] = ex[k] * inv;
    }
    __syncthreads();
    // per-group scale = 1 / sum_t weights
    if (tid < KBINS) {
        float s = 0.f;
        for (int t = 0; t < TT; t++) s += wts[t][tid];
        kfac[tid] = (s > 0.f) ? (1.0f / s) : 1.0f;
    }
    __syncthreads();
    if (tid < TT * KBINS) {
        int t = tid >> 2, k = tid & 3;
        nw[((size_t)b * TT + t) * KBINS + k] = wts[t][k] * kfac[k];
    }
}

// ---------------------------------------------------------------------------
// Kernel D: out[b,c,k,hw] = sum_t x[b,c,t,hw] * nw[b,t,k]
// One block per (b,c); thread per float4 position (196 active of 256).
// ---------------------------------------------------------------------------
__global__ void out_kernel(const float* __restrict__ x, const float* __restrict__ nw,
                           float* __restrict__ out) {
    __shared__ float w[TT * KBINS];
    const int b = blockIdx.x >> 8;
    const int c = blockIdx.x & 255;
    if (threadIdx.x < TT * KBINS) w[threadIdx.x] = nw[(size_t)b * TT * KBINS + threadIdx.x];
    __syncthreads();
    const int f = threadIdx.x;
    if (f >= 196) return;
    const float4* xp = (const float4*)(x + ((size_t)(b * CCH + c) * TT) * HWSZ);
    float4 acc[KBINS];
#pragma unroll
    for (int k = 0; k < KBINS; k++) { acc[k].x = 0.f; acc[k].y = 0.f; acc[k].z = 0.f; acc[k].w = 0.f; }
#pragma unroll 8
    for (int t = 0; t < TT; t++) {
        float4 v = xp[t * 196 + f];
#pragma unroll
        for (int k = 0; k < KBINS; k++) {
            float wk = w[t * KBINS + k];
            acc[k].x += v.x * wk;
            acc[k].y += v.y * wk;
            acc[k].z += v.z * wk;
            acc[k].w += v.w * wk;
        }
    }
    float4* op = (float4*)(out + ((size_t)(b * CCH + c) * KBINS) * HWSZ);
#pragma unroll
    for (int k = 0; k < KBINS; k++) op[k * 196 + f] = acc[k];
}

extern "C" void kernel_launch(void* const* d_in, const int* in_sizes, int n_in,
                              void* d_out, int out_size, void* d_ws, size_t ws_size,
                              hipStream_t stream) {
    const float* x  = (const float*)d_in[0];
    const float* W1 = (const float*)d_in[1];
    const float* b1 = (const float*)d_in[2];
    const float* W2 = (const float*)d_in[3];
    const float* b2 = (const float*)d_in[4];
    float* out = (float*)d_out;

    float* ws     = (float*)d_ws;
    float* pooled = ws;                                // B*C*T   = 65536
    float* h      = pooled + BATCH * CCH * TT;         // B*HID*T = 131072
    float* embds  = h + BATCH * HID * TT;              // B*EMB*T = 8192
    float* nw     = embds + BATCH * EMB * TT;          // B*T*K   = 1024

    pool_kernel<<<BATCH * CCH * TT / 4, 256, 0, stream>>>(x, pooled);
    fc1_kernel<<<BATCH * 64, 256, 0, stream>>>(W1, b1, pooled, h);
    fc2_kernel<<<BATCH * EMB * TT / 256, 256, 0, stream>>>(W2, b2, h, embds);
    group_kernel<<<BATCH, 256, 0, stream>>>(embds, nw);
    out_kernel<<<BATCH * CCH, 256, 0, stream>>>(x, nw, out);
}

// Round 3
// 346.876 us; speedup vs baseline: 1.1402x; 1.0402x over previous
//
#include <hip/hip_runtime.h>
#include <math.h>

#define BATCH 8
#define CCH   256
#define TT    32
#define HWSZ  784      // 28*28
#define HID   512
#define EMB   32
#define KBINS 4
#define SCALEF 5.0f
#define EPSN  1e-12f

// ---------------------------------------------------------------------------
// Kernel 1 (fused): per (b,t) column — pool over HW, fc1+hswish, fc2.
// Block = 1024 threads (16 waves). Grid = B*T = 256 blocks.
//   phase 1: 16 waves each pool 16 channels (float4 coalesced, shuffle reduce)
//   phase 2: threads 0..511 compute h[hid] (dot-256 vs LDS pooled column)
//   phase 3: 32 lanes-groups compute embds[e] (dot-512 vs LDS h column)
// ---------------------------------------------------------------------------
__global__ __launch_bounds__(1024) void mlp_kernel(
        const float* __restrict__ x,
        const float* __restrict__ W1, const float* __restrict__ b1,
        const float* __restrict__ W2, const float* __restrict__ b2,
        float* __restrict__ embds) {
    __shared__ float pcol[CCH];
    __shared__ float hcol[HID];

    const int b = blockIdx.x >> 5;       // blockIdx = b*TT + t
    const int t = blockIdx.x & 31;
    const int tid  = threadIdx.x;
    const int wave = tid >> 6;
    const int lane = tid & 63;

    // phase 1: pooled[c] = mean(x[b,c,t,:,:])
    for (int c = wave; c < CCH; c += 16) {
        const float4* xp = (const float4*)(x + ((size_t)((b * CCH + c) * TT + t)) * HWSZ);
        float s = 0.f;
        for (int f = lane; f < 196; f += 64) {
            float4 v = xp[f];
            s += v.x + v.y + v.z + v.w;
        }
#pragma unroll
        for (int off = 32; off > 0; off >>= 1) s += __shfl_down(s, off);
        if (lane == 0) pcol[c] = s * (1.0f / 784.0f);
    }
    __syncthreads();

    // phase 2: h[hid] = hswish(W1[hid,:]·pcol + b1[hid])
    if (tid < HID) {
        const float4* w = (const float4*)(W1 + (size_t)tid * CCH);
        float acc = 0.f;
#pragma unroll 8
        for (int j = 0; j < CCH / 4; j++) {
            float4 wv = w[j];
            acc += wv.x * pcol[4 * j] + wv.y * pcol[4 * j + 1]
                 + wv.z * pcol[4 * j + 2] + wv.w * pcol[4 * j + 3];
        }
        acc += b1[tid];
        float r = fminf(fmaxf(acc + 3.0f, 0.0f), 6.0f);
        hcol[tid] = acc * r * (1.0f / 6.0f);
    }
    __syncthreads();

    // phase 3: embds[e] = W2[e,:]·hcol + b2[e]; 32 threads per e
    {
        const int e = tid >> 5;          // 0..31
        const int l = tid & 31;
        const float* w = W2 + (size_t)e * HID;
        float acc = 0.f;
#pragma unroll
        for (int j = 0; j < HID / 32; j++) acc += w[l + 32 * j] * hcol[l + 32 * j];
        // reduce within each 32-lane half
        acc += __shfl_down(acc, 16);
        acc += __shfl_down(acc, 8);
        acc += __shfl_down(acc, 4);
        acc += __shfl_down(acc, 2);
        acc += __shfl_down(acc, 1);
        if (l == 0) embds[((size_t)b * EMB + e) * TT + t] = acc + b2[e];
    }
}

// ---------------------------------------------------------------------------
// Kernel 2: one block per batch. l2norm -> neighbor sims -> 3rd-smallest
// threshold (top_k incl. duplicates) -> grouping -> centers -> l2norm ->
// similarities -> softmax -> per-group weight norm. Writes nw[b][t][k].
// ---------------------------------------------------------------------------
__global__ void group_kernel(const float* __restrict__ embds, float* __restrict__ nw) {
    __shared__ float se[EMB][TT + 1];
    __shared__ float ns[TT];
    __shared__ float tmpns[TT];
    __shared__ float colinv[TT];
    __shared__ float cs[EMB][KBINS];
    __shared__ float wts[TT][KBINS];
    __shared__ float gsize[KBINS];
    __shared__ float kfac[KBINS];
    __shared__ int   gid[TT];

    const int b   = blockIdx.x;
    const int tid = threadIdx.x;

    for (int i = tid; i < EMB * TT; i += 256)
        se[i >> 5][i & 31] = embds[(size_t)b * EMB * TT + i];
    __syncthreads();

    if (tid < TT) {
        float s = 0.f;
        for (int e = 0; e < EMB; e++) { float v = se[e][tid]; s += v * v; }
        colinv[tid] = 1.0f / fmaxf(sqrtf(s), EPSN);
    }
    __syncthreads();
    for (int i = tid; i < EMB * TT; i += 256) {
        int e = i >> 5, t = i & 31;
        se[e][t] *= colinv[t];
    }
    __syncthreads();

    if (tid < TT - 1) {
        float s = 0.f;
        for (int e = 0; e < EMB; e++) s += se[e][tid] * se[e][tid + 1];
        ns[tid] = s;
    }
    __syncthreads();

    if (tid == 0) {
        for (int i = 0; i < TT - 1; i++) tmpns[i] = ns[i];
        float thr = 0.f;
        for (int p = 0; p < KBINS - 1; p++) {
            int jm = 0; float m = tmpns[0];
            for (int i = 1; i < TT - 1; i++) if (tmpns[i] < m) { m = tmpns[i]; jm = i; }
            thr = m;
            tmpns[jm] = __builtin_inff();
        }
        int g = 0; gid[0] = 0;
        for (int t = 1; t < TT; t++) { if (!(ns[t - 1] > thr)) g++; gid[t] = g; }
        for (int k = 0; k < KBINS; k++) {
            float c = 0.f;
            for (int t = 0; t < TT; t++) if (gid[t] == k) c += 1.0f;
            gsize[k] = c;
        }
    }
    __syncthreads();

    if (tid < EMB * KBINS) {
        int e = tid >> 2, k = tid & 3;
        float s = 0.f;
        for (int t = 0; t < TT; t++) if (gid[t] == k) s += se[e][t];
        cs[e][k] = s / gsize[k];
    }
    __syncthreads();
    if (tid < KBINS) {
        float s = 0.f;
        for (int e = 0; e < EMB; e++) { float v = cs[e][tid]; s += v * v; }
        kfac[tid] = 1.0f / fmaxf(sqrtf(s), EPSN);
    }
    __syncthreads();
    if (tid < EMB * KBINS) {
        int e = tid >> 2, k = tid & 3;
        cs[e][k] *= kfac[k];
    }
    __syncthreads();

    if (tid < TT * KBINS) {
        int t = tid >> 2, k = tid & 3;
        float s = 0.f;
        for (int e = 0; e < EMB; e++) s += se[e][t] * cs[e][k];
        wts[t][k] = s * SCALEF;
    }
    __syncthreads();
    if (tid < TT) {
        float m = wts[tid][0];
        for (int k = 1; k < KBINS; k++) m = fmaxf(m, wts[tid][k]);
        float ex[KBINS]; float sum = 0.f;
        for (int k = 0; k < KBINS; k++) { ex[k] = expf(wts[tid][k] - m); sum += ex[k]; }
        float inv = 1.0f / sum;
        for (int k = 0; k < KBINS; k++) wts[tid][k] = ex[k] * inv;
    }
    __syncthreads();
    if (tid < KBINS) {
        float s = 0.f;
        for (int t = 0; t < TT; t++) s += wts[t][tid];
        kfac[tid] = (s > 0.f) ? (1.0f / s) : 1.0f;
    }
    __syncthreads();
    if (tid < TT * KBINS) {
        int t = tid >> 2, k = tid & 3;
        nw[((size_t)b * TT + t) * KBINS + k] = wts[t][k] * kfac[k];
    }
}

// ---------------------------------------------------------------------------
// Kernel 3: out[b,c,k,hw4] = sum_t x[b,c,t,hw4] * nw[b,t,k]
// Flat thread mapping over (c, f): 196 float4 per (b,c), 100% lane use.
// b is block-uniform (256*196 threads per b, 196 blocks of 256 per b).
// ---------------------------------------------------------------------------
__global__ void out_kernel(const float* __restrict__ x, const float* __restrict__ nw,
                           float* __restrict__ out) {
    __shared__ float w[TT * KBINS];
    const int b = blockIdx.x / 196;
    const unsigned idx = (blockIdx.x % 196) * 256 + threadIdx.x;   // [0, 50176)
    if (threadIdx.x < TT * KBINS) w[threadIdx.x] = nw[(size_t)b * TT * KBINS + threadIdx.x];
    __syncthreads();
    const unsigned c = idx / 196;
    const unsigned f = idx % 196;
    const float4* xp = (const float4*)(x + ((size_t)(b * CCH + c) * TT) * HWSZ);
    float4 acc[KBINS];
#pragma unroll
    for (int k = 0; k < KBINS; k++) { acc[k].x = 0.f; acc[k].y = 0.f; acc[k].z = 0.f; acc[k].w = 0.f; }
#pragma unroll 8
    for (int t = 0; t < TT; t++) {
        float4 v = xp[t * 196 + f];
#pragma unroll
        for (int k = 0; k < KBINS; k++) {
            float wk = w[t * KBINS + k];
            acc[k].x += v.x * wk;
            acc[k].y += v.y * wk;
            acc[k].z += v.z * wk;
            acc[k].w += v.w * wk;
        }
    }
    float4* op = (float4*)(out + ((size_t)(b * CCH + c) * KBINS) * HWSZ);
#pragma unroll
    for (int k = 0; k < KBINS; k++) op[k * 196 + f] = acc[k];
}

extern "C" void kernel_launch(void* const* d_in, const int* in_sizes, int n_in,
                              void* d_out, int out_size, void* d_ws, size_t ws_size,
                              hipStream_t stream) {
    const float* x  = (const float*)d_in[0];
    const float* W1 = (const float*)d_in[1];
    const float* b1 = (const float*)d_in[2];
    const float* W2 = (const float*)d_in[3];
    const float* b2 = (const float*)d_in[4];
    float* out = (float*)d_out;

    float* ws    = (float*)d_ws;
    float* embds = ws;                         // B*EMB*T = 8192
    float* nw    = embds + BATCH * EMB * TT;   // B*T*K   = 1024

    mlp_kernel<<<BATCH * TT, 1024, 0, stream>>>(x, W1, b1, W2, b2, embds);
    group_kernel<<<BATCH, 256, 0, stream>>>(embds, nw);
    out_kernel<<<BATCH * 196, 256, 0, stream>>>(x, nw, out);
}

// Round 4
// 345.399 us; speedup vs baseline: 1.1450x; 1.0043x over previous
//
#include <hip/hip_runtime.h>
#include <math.h>

#define BATCH 8
#define CCH   256
#define TT    32
#define HWSZ  784      // 28*28
#define HID   512
#define EMB   32
#define KBINS 4
#define SCALEF 5.0f
#define EPSN  1e-12f

// ---------------------------------------------------------------------------
// Kernel 1 (fused): per (b,t) column — pool over HW, fc1+hswish, fc2.
// Block = 1024 threads (16 waves). Grid = B*T = 256 blocks (1/CU).
// ---------------------------------------------------------------------------
__global__ __launch_bounds__(1024) void mlp_kernel(
        const float* __restrict__ x,
        const float* __restrict__ W1, const float* __restrict__ b1,
        const float* __restrict__ W2, const float* __restrict__ b2,
        float* __restrict__ embds) {
    __shared__ float pcol[CCH];
    __shared__ float hcol[HID];

    const int b = blockIdx.x >> 5;       // blockIdx = b*TT + t
    const int t = blockIdx.x & 31;
    const int tid  = threadIdx.x;
    const int wave = tid >> 6;
    const int lane = tid & 63;

    // phase 1: pooled[c] = mean(x[b,c,t,:,:]) — wave per channel, float4 loads
    for (int c = wave; c < CCH; c += 16) {
        const float4* xp = (const float4*)(x + ((size_t)((b * CCH + c) * TT + t)) * HWSZ);
        float s = 0.f;
        for (int f = lane; f < 196; f += 64) {
            float4 v = xp[f];
            s += v.x + v.y + v.z + v.w;
        }
#pragma unroll
        for (int off = 32; off > 0; off >>= 1) s += __shfl_down(s, off);
        if (lane == 0) pcol[c] = s * (1.0f / 784.0f);
    }
    __syncthreads();

    // phase 2: h[hid] = hswish(W1[hid,:]·pcol + b1[hid])
    if (tid < HID) {
        const float4* w = (const float4*)(W1 + (size_t)tid * CCH);
        float acc = 0.f;
#pragma unroll 8
        for (int j = 0; j < CCH / 4; j++) {
            float4 wv = w[j];
            acc += wv.x * pcol[4 * j] + wv.y * pcol[4 * j + 1]
                 + wv.z * pcol[4 * j + 2] + wv.w * pcol[4 * j + 3];
        }
        acc += b1[tid];
        float r = fminf(fmaxf(acc + 3.0f, 0.0f), 6.0f);
        hcol[tid] = acc * r * (1.0f / 6.0f);
    }
    __syncthreads();

    // phase 3: embds[e] = W2[e,:]·hcol + b2[e]; 32 threads per e
    {
        const int e = tid >> 5;          // 0..31
        const int l = tid & 31;
        const float* w = W2 + (size_t)e * HID;
        float acc = 0.f;
#pragma unroll
        for (int j = 0; j < HID / 32; j++) acc += w[l + 32 * j] * hcol[l + 32 * j];
        acc += __shfl_down(acc, 16);
        acc += __shfl_down(acc, 8);
        acc += __shfl_down(acc, 4);
        acc += __shfl_down(acc, 2);
        acc += __shfl_down(acc, 1);
        if (l == 0) embds[((size_t)b * EMB + e) * TT + t] = acc + b2[e];
    }
}

// ---------------------------------------------------------------------------
// Kernel 2: one block per batch — fully parallel middle (no serial thread-0
// scan): l2norm -> neighbor sims -> rank-count 3rd-smallest threshold
// (top_k-with-duplicates semantics) -> per-thread prefix grouping -> centers
// -> l2norm -> similarities -> softmax -> per-group weight norm.
// ---------------------------------------------------------------------------
__global__ void group_kernel(const float* __restrict__ embds, float* __restrict__ nw) {
    __shared__ float se[EMB][TT + 1];
    __shared__ float ns[TT];
    __shared__ float colinv[TT];
    __shared__ float thr_sh;
    __shared__ float cs[EMB][KBINS];
    __shared__ float wts[TT][KBINS];
    __shared__ float gsize[KBINS];
    __shared__ float kfac[KBINS];
    __shared__ int   gid[TT];

    const int b   = blockIdx.x;
    const int tid = threadIdx.x;

    for (int i = tid; i < EMB * TT; i += 256)
        se[i >> 5][i & 31] = embds[(size_t)b * EMB * TT + i];
    __syncthreads();

    // column l2 norms over e
    if (tid < TT) {
        float s = 0.f;
        for (int e = 0; e < EMB; e++) { float v = se[e][tid]; s += v * v; }
        colinv[tid] = 1.0f / fmaxf(sqrtf(s), EPSN);
    }
    __syncthreads();
    for (int i = tid; i < EMB * TT; i += 256) {
        int e = i >> 5, t = i & 31;
        se[e][t] *= colinv[t];
    }
    __syncthreads();

    // neighbor similarities ns[t] = <ne[:,t], ne[:,t+1]>
    if (tid < TT - 1) {
        float s = 0.f;
        for (int e = 0; e < EMB; e++) s += se[e][tid] * se[e][tid + 1];
        ns[tid] = s;
    }
    __syncthreads();

    // threshold = element with stable sorted rank 2 (3rd smallest, dup-aware)
    if (tid < TT - 1) {
        float v = ns[tid];
        int pos = 0;
        for (int j = 0; j < TT - 1; j++) {
            float u = ns[j];
            pos += (u < v) || (u == v && j < tid);
        }
        if (pos == KBINS - 2) thr_sh = v;   // exactly one thread matches
    }
    __syncthreads();

    // gid[t] = #breaks in [1,t]; break at s iff !(ns[s-1] > thr)
    if (tid < TT) {
        float thr = thr_sh;
        int g = 0;
        for (int s = 1; s <= tid; s++) g += !(ns[s - 1] > thr);
        gid[tid] = g;
    }
    __syncthreads();
    if (tid < KBINS) {
        float c = 0.f;
        for (int t = 0; t < TT; t++) c += (gid[t] == tid);
        gsize[tid] = c;
    }
    __syncthreads();

    // centers_sum / size
    if (tid < EMB * KBINS) {
        int e = tid >> 2, k = tid & 3;
        float s = 0.f;
        for (int t = 0; t < TT; t++) if (gid[t] == k) s += se[e][t];
        cs[e][k] = s / gsize[k];
    }
    __syncthreads();
    if (tid < KBINS) {
        float s = 0.f;
        for (int e = 0; e < EMB; e++) { float v = cs[e][tid]; s += v * v; }
        kfac[tid] = 1.0f / fmaxf(sqrtf(s), EPSN);
    }
    __syncthreads();
    if (tid < EMB * KBINS) {
        int e = tid >> 2, k = tid & 3;
        cs[e][k] *= kfac[k];
    }
    __syncthreads();

    // similarities (scaled)
    if (tid < TT * KBINS) {
        int t = tid >> 2, k = tid & 3;
        float s = 0.f;
        for (int e = 0; e < EMB; e++) s += se[e][t] * cs[e][k];
        wts[t][k] = s * SCALEF;
    }
    __syncthreads();
    // softmax over k per t
    if (tid < TT) {
        float m = wts[tid][0];
        for (int k = 1; k < KBINS; k++) m = fmaxf(m, wts[tid][k]);
        float ex[KBINS]; float sum = 0.f;
        for (int k = 0; k < KBINS; k++) { ex[k] = expf(wts[tid][k] - m); sum += ex[k]; }
        float inv = 1.0f / sum;
        for (int k = 0; k < KBINS; k++) wts[tid][k] = ex[k] * inv;
    }
    __syncthreads();
    if (tid < KBINS) {
        float s = 0.f;
        for (int t = 0; t < TT; t++) s += wts[t][tid];
        kfac[tid] = (s > 0.f) ? (1.0f / s) : 1.0f;
    }
    __syncthreads();
    if (tid < TT * KBINS) {
        int t = tid >> 2, k = tid & 3;
        nw[((size_t)b * TT + t) * KBINS + k] = wts[t][k] * kfac[k];
    }
}

// ---------------------------------------------------------------------------
// Kernel 3: out[b,c,k,hw4] = sum_t x[b,c,t,hw4] * nw[b,t,k]
// 128-thread blocks (finer tail quantum: 3136 blocks = 12.25/CU).
// b is block-uniform: 50176 float4-tasks per b = 392 blocks of 128 exactly.
// ---------------------------------------------------------------------------
__global__ __launch_bounds__(128) void out_kernel(
        const float* __restrict__ x, const float* __restrict__ nw,
        float* __restrict__ out) {
    __shared__ float w[TT * KBINS];
    const int b = blockIdx.x / 392;
    const unsigned idx = (blockIdx.x % 392) * 128 + threadIdx.x;   // [0, 50176)
    w[threadIdx.x] = nw[(size_t)b * TT * KBINS + threadIdx.x];
    __syncthreads();
    const unsigned c = idx / 196;
    const unsigned f = idx % 196;
    const float4* xp = (const float4*)(x + ((size_t)(b * CCH + c) * TT) * HWSZ);
    float4 acc[KBINS];
#pragma unroll
    for (int k = 0; k < KBINS; k++) { acc[k].x = 0.f; acc[k].y = 0.f; acc[k].z = 0.f; acc[k].w = 0.f; }
#pragma unroll 8
    for (int t = 0; t < TT; t++) {
        float4 v = xp[t * 196 + f];
#pragma unroll
        for (int k = 0; k < KBINS; k++) {
            float wk = w[t * KBINS + k];
            acc[k].x += v.x * wk;
            acc[k].y += v.y * wk;
            acc[k].z += v.z * wk;
            acc[k].w += v.w * wk;
        }
    }
    float4* op = (float4*)(out + ((size_t)(b * CCH + c) * KBINS) * HWSZ);
#pragma unroll
    for (int k = 0; k < KBINS; k++) op[k * 196 + f] = acc[k];
}

extern "C" void kernel_launch(void* const* d_in, const int* in_sizes, int n_in,
                              void* d_out, int out_size, void* d_ws, size_t ws_size,
                              hipStream_t stream) {
    const float* x  = (const float*)d_in[0];
    const float* W1 = (const float*)d_in[1];
    const float* b1 = (const float*)d_in[2];
    const float* W2 = (const float*)d_in[3];
    const float* b2 = (const float*)d_in[4];
    float* out = (float*)d_out;

    float* ws    = (float*)d_ws;
    float* embds = ws;                         // B*EMB*T = 8192
    float* nw    = embds + BATCH * EMB * TT;   // B*T*K   = 1024

    mlp_kernel<<<BATCH * TT, 1024, 0, stream>>>(x, W1, b1, W2, b2, embds);
    group_kernel<<<BATCH, 256, 0, stream>>>(embds, nw);
    out_kernel<<<BATCH * 392, 128, 0, stream>>>(x, nw, out);
}